// Round 4
// baseline (380.921 us; speedup 1.0000x reference)
//
#include <hip/hip_runtime.h>

#define N_NODES 100000
#define DIM 128
#define N_REL 8
#define N_EDGES 625000
#define RN 800000            // N_REL * N_NODES (keys r*N+d)
#define NCH 3125             // RN / 256 exactly
#define N_PADROWS 100032     // 1563 blocks * 64 rows

// fp32 -> bf16, round-to-nearest-even
__device__ __forceinline__ unsigned short f2bf(float f) {
    unsigned int u = __float_as_uint(f);
    u += 0x7fffu + ((u >> 16) & 1u);
    return (unsigned short)(u >> 16);
}

__device__ __forceinline__ float bf2f(unsigned short s) {
    return __uint_as_float(((unsigned int)s) << 16);
}

// prep: x->bf16 (12.8M elems, 4/thread, exact grid), zero degi, zero xb pad rows,
// convert W into MFMA B-fragment order (r<8 rel, r==8 selfloop).
__global__ __launch_bounds__(256) void prep_kernel(const float* __restrict__ x,
                                                   const float* __restrict__ relw,
                                                   const float* __restrict__ selfw,
                                                   unsigned short* __restrict__ xb,
                                                   unsigned short* __restrict__ Wt,
                                                   int* __restrict__ degi) {
    int i = blockIdx.x * 256 + threadIdx.x;      // 0 .. 3,200,000-1 exact
    {
        float4 v = *(const float4*)(x + (size_t)i * 4);
        unsigned short t[4] = {f2bf(v.x), f2bf(v.y), f2bf(v.z), f2bf(v.w)};
        *(uint2*)(xb + (size_t)i * 4) = *(const uint2*)t;
    }
    if (i < RN) degi[i] = 0;
    if (i < 512) {  // zero pad rows 100000..100031 (4096 shorts)
        uint4 z = {0, 0, 0, 0};
        *(uint4*)(xb + (size_t)N_NODES * DIM + i * 8) = z;
    }
    if (i < 147456) {  // Wt[(((r*4+ks)*8+t)*64+lane)*8+j] = W_r[din=ks*32+quad*8+j][dout=t*16+m16]
        int j = i & 7;
        int lane = (i >> 3) & 63;
        int t = (i >> 9) & 7;
        int ks = (i >> 12) & 3;
        int r = i >> 14;
        int m16 = lane & 15, quad = lane >> 4;
        int din = ks * 32 + quad * 8 + j;
        int dout = t * 16 + m16;
        float v = (r < 8) ? relw[(r << 14) + (din << 7) + dout] : selfw[(din << 7) + dout];
        Wt[i] = f2bf(v);
    }
}

// Per-(rel,dst) histogram with key r*N+d (this IS the degree).
__global__ __launch_bounds__(256) void hist_kernel(const int* __restrict__ dst,
                                                   const int* __restrict__ rel,
                                                   int* __restrict__ degi) {
    int e = blockIdx.x * 256 + threadIdx.x;
    if (e < N_EDGES) atomicAdd(&degi[rel[e] * N_NODES + dst[e]], 1);
}

__global__ __launch_bounds__(256) void scan1_kernel(const int* __restrict__ cnt,
                                                    int* __restrict__ bsum) {
    __shared__ int l[256];
    int t = threadIdx.x;
    l[t] = cnt[blockIdx.x * 256 + t];
    __syncthreads();
    for (int off = 128; off > 0; off >>= 1) {
        if (t < off) l[t] += l[t + off];
        __syncthreads();
    }
    if (t == 0) bsum[blockIdx.x] = l[0];
}

// Exclusive scan of bsum[3125]: 13/thread serial + Hillis-Steele over 256 partials.
__global__ __launch_bounds__(256) void scan2_kernel(int* __restrict__ bsum) {
    __shared__ int part[256];
    int t = threadIdx.x;
    int base = t * 13;
    int v[13];
    int sum = 0;
#pragma unroll
    for (int j = 0; j < 13; j++) {
        int idx = base + j;
        int x = (idx < NCH) ? bsum[idx] : 0;
        v[j] = sum;
        sum += x;
    }
    part[t] = sum;
    __syncthreads();
    for (int off = 1; off < 256; off <<= 1) {
        int p = (t >= off) ? part[t - off] : 0;
        __syncthreads();
        part[t] += p;
        __syncthreads();
    }
    int excl = part[t] - sum;
#pragma unroll
    for (int j = 0; j < 13; j++) {
        int idx = base + j;
        if (idx < NCH) bsum[idx] = excl + v[j];
    }
}

__global__ __launch_bounds__(256) void scan3_kernel(const int* __restrict__ cnt,
                                                    const int* __restrict__ bsum,
                                                    int* __restrict__ offs,
                                                    int* __restrict__ cursor) {
    __shared__ int l[256];
    int t = threadIdx.x;
    int i = blockIdx.x * 256 + t;
    int c = cnt[i];
    l[t] = c;
    __syncthreads();
    for (int off = 1; off < 256; off <<= 1) {
        int v = (t >= off) ? l[t - off] : 0;
        __syncthreads();
        l[t] += v;
        __syncthreads();
    }
    int excl = l[t] - c + bsum[blockIdx.x];
    offs[i] = excl;
    cursor[i] = excl;
    if (i == RN - 1) offs[RN] = excl + c;   // sentinel: total edge count
}

// Bin edges by key r*N+d; slot word = src | deg<<17 (deg shared by the segment).
__global__ __launch_bounds__(256) void fill_kernel(const int* __restrict__ src,
                                                   const int* __restrict__ dst,
                                                   const int* __restrict__ rel,
                                                   const int* __restrict__ degi,
                                                   int* __restrict__ cursor,
                                                   unsigned int* __restrict__ ebuf) {
    int e = blockIdx.x * 256 + threadIdx.x;
    if (e < N_EDGES) {
        int key = rel[e] * N_NODES + dst[e];
        int pos = atomicAdd(&cursor[key], 1);
        int dg = degi[key];
        if (dg > 32767) dg = 32767;
        ebuf[pos] = (unsigned int)src[e] | ((unsigned int)dg << 17);
    }
}

typedef __attribute__((ext_vector_type(8))) short frag8;
typedef __attribute__((ext_vector_type(4))) float f32x4;

// Fully fused aggregate+transform. Block = 64 dst rows, wave owns 16 rows.
// Per relation: build wave-private 16x128 bf16 Agg tile in LDS (XOR-swizzled
// 256B rows) from CSR segments gathering L3-resident xb, then MFMA vs Wt[r].
// Selfloop A-frags come straight from xb. Zero barriers; one out write.
__global__ __launch_bounds__(256, 4) void fused_kernel(const unsigned short* __restrict__ xb,
                                                       const unsigned short* __restrict__ Wt,
                                                       const int* __restrict__ offs2,
                                                       const unsigned int* __restrict__ ebuf,
                                                       const float* __restrict__ bias,
                                                       float* __restrict__ out) {
    __shared__ __align__(16) unsigned char ldsraw[4 * 8448];   // 33 KB

    const int tid = threadIdx.x;
    const int wave = tid >> 6, lane = tid & 63;
    const int m16 = lane & 15, quad = lane >> 4;
    const int dbase = blockIdx.x * 64 + wave * 16;   // this wave's 16 dst rows
    unsigned char* slab = ldsraw + wave * 8448;

    f32x4 acc[8];
    // ---- selfloop (r==8): A-frags direct from xb (pad rows are zeroed) ----
    {
#pragma unroll
        for (int t = 0; t < 8; t++) acc[t] = (f32x4){0.f, 0.f, 0.f, 0.f};
        const unsigned short* ap = xb + (size_t)(dbase + m16) * DIM;
#pragma unroll
        for (int ks = 0; ks < 4; ks++) {
            frag8 a = *(const frag8*)(ap + ks * 32 + quad * 8);
            const frag8* bp = (const frag8*)Wt + ((8 * 4 + ks) * 8) * 64 + lane;
#pragma unroll
            for (int t = 0; t < 8; t++)
                acc[t] = __builtin_amdgcn_mfma_f32_16x16x32_bf16(a, bp[t * 64], acc[t], 0, 0, 0);
        }
    }

    // ---- relations 0..7 ----
#pragma unroll 1
    for (int r = 0; r < 8; r++) {
        int cidx = dbase + lane;
        if (cidx > N_NODES) cidx = N_NODES;          // clamp -> empty segments for pad rows
        int ob = offs2[r * N_NODES + cidx];          // lanes 0..16 meaningful

        // build Agg: 16 segments, register-accumulate, one swizzled LDS write each
#pragma unroll 1
        for (int dl = 0; dl < 16; dl++) {
            int s = __shfl(ob, dl);
            int e1 = __shfl(ob, dl + 1);
            float ax = 0.f, ay = 0.f;
            unsigned int deg = 1;
            for (int ie = s; ie < e1; ie++) {
                unsigned int de = ebuf[ie];          // wave-uniform broadcast load
                deg = de >> 17;
                const unsigned int* rowp = (const unsigned int*)(xb + (size_t)(de & 0x1ffffu) * DIM);
                unsigned int v = rowp[lane];         // 2 bf16, 256B/wave coalesced, L3-hot
                ax += bf2f((unsigned short)(v & 0xffffu));
                ay += bf2f((unsigned short)(v >> 16));
            }
            float inv = 1.0f / (float)deg;
            ax *= inv; ay *= inv;
            unsigned int packed = (unsigned int)f2bf(ax) | ((unsigned int)f2bf(ay) << 16);
            int b = (lane >> 2) ^ dl;                // XOR swizzle of 16B blocks
            *(unsigned int*)(slab + dl * 256 + b * 16 + (lane & 3) * 4) = packed;
        }

        // A-frags from swizzled slab (16B-aligned b128, bank-balanced) + MFMA
#pragma unroll
        for (int ks = 0; ks < 4; ks++) {
            int b = (4 * ks + quad) ^ m16;
            frag8 a = *(const frag8*)(slab + m16 * 256 + b * 16);
            const frag8* bp = (const frag8*)Wt + ((r * 4 + ks) * 8) * 64 + lane;
#pragma unroll
            for (int t = 0; t < 8; t++)
                acc[t] = __builtin_amdgcn_mfma_f32_16x16x32_bf16(a, bp[t * 64], acc[t], 0, 0, 0);
        }
    }

    // ---- epilogue: +bias, wave-private repack (fp32, stride 132), coalesced store
    float* S = (float*)slab;
#pragma unroll
    for (int t = 0; t < 8; t++) {
        float bc = bias[t * 16 + m16];
#pragma unroll
        for (int i = 0; i < 4; i++)
            S[(quad * 4 + i) * 132 + t * 16 + m16] = acc[t][i] + bc;
    }
#pragma unroll
    for (int c = 0; c < 8; c++) {
        int row16 = c * 2 + (lane >> 5);
        int g = dbase + row16;
        if (g < N_NODES)
            *(float4*)(out + (size_t)g * DIM + (lane & 31) * 4) =
                *(float4*)(S + row16 * 132 + (lane & 31) * 4);
    }
}

extern "C" void kernel_launch(void* const* d_in, const int* in_sizes, int n_in,
                              void* d_out, int out_size, void* d_ws, size_t ws_size,
                              hipStream_t stream) {
    const float* x = (const float*)d_in[0];
    const int* edge_index = (const int*)d_in[1]; // [2][E]: src then dst
    const int* edge_type = (const int*)d_in[2];
    const float* relw = (const float*)d_in[3];
    const float* selfw = (const float*)d_in[4];
    const float* bias = (const float*)d_in[5];
    float* out = (float*)d_out;
    (void)in_sizes; (void)n_in; (void)out_size; (void)ws_size;

    // ws: xb 25.6MB | Wt 0.29MB | offs2 3.2MB | ebuf 2.5MB  (~31.6 MB)
    char* ws = (char*)d_ws;
    size_t off = 0;
    unsigned short* xb = (unsigned short*)(ws + off); off += (size_t)N_PADROWS * DIM * 2;
    unsigned short* Wt = (unsigned short*)(ws + off); off += (size_t)9 * DIM * DIM * 2;
    int* offs2 = (int*)(ws + off); off += (size_t)(RN + 4) * 4;
    unsigned int* ebuf = (unsigned int*)(ws + off); off += (size_t)N_EDGES * 4;

    // pre-fused scratch in d_out (fused_kernel overwrites all of out at the end)
    int* degi = (int*)d_out;              // 3.2 MB
    int* cursor = degi + RN;              // 3.2 MB
    int* bsum = cursor + RN;              // 12.5 KB

    const int* src = edge_index;
    const int* dst = edge_index + N_EDGES;

    prep_kernel<<<12500, 256, 0, stream>>>(x, relw, selfw, xb, Wt, degi);
    hist_kernel<<<(N_EDGES + 255) / 256, 256, 0, stream>>>(dst, edge_type, degi);
    scan1_kernel<<<NCH, 256, 0, stream>>>(degi, bsum);
    scan2_kernel<<<1, 256, 0, stream>>>(bsum);
    scan3_kernel<<<NCH, 256, 0, stream>>>(degi, bsum, offs2, cursor);
    fill_kernel<<<(N_EDGES + 255) / 256, 256, 0, stream>>>(src, dst, edge_type, degi, cursor, ebuf);
    fused_kernel<<<N_PADROWS / 64, 256, 0, stream>>>(xb, Wt, offs2, ebuf, bias, out);
}

// Round 5
// 283.485 us; speedup vs baseline: 1.3437x; 1.3437x over previous
//
#include <hip/hip_runtime.h>

#define N_NODES 100000
#define DIM 128
#define N_REL 8
#define N_EDGES 625000
#define RN 800000            // N_REL * N_NODES (keys r*N+d)
#define N_PADROWS 100032     // 1563 blocks * 64 rows
#define SCAN_BLOCKS 98
#define SCAN_CHUNK 8192      // 256 threads * 32 elems

// fp32 -> bf16, round-to-nearest-even
__device__ __forceinline__ unsigned short f2bf(float f) {
    unsigned int u = __float_as_uint(f);
    u += 0x7fffu + ((u >> 16) & 1u);
    return (unsigned short)(u >> 16);
}

__device__ __forceinline__ float bf2f(unsigned short s) {
    return __uint_as_float(((unsigned int)s) << 16);
}

// prep: x->bf16 (12.8M elems, 4/thread, exact grid), zero xb pad rows,
// W -> MFMA B-frag order, and the (rel,dst) histogram (degi pre-zeroed by memset).
__global__ __launch_bounds__(256) void prep_kernel(const float* __restrict__ x,
                                                   const float* __restrict__ relw,
                                                   const float* __restrict__ selfw,
                                                   const int* __restrict__ dst,
                                                   const int* __restrict__ rel,
                                                   unsigned short* __restrict__ xb,
                                                   unsigned short* __restrict__ Wt,
                                                   int* __restrict__ degi) {
    int i = blockIdx.x * 256 + threadIdx.x;      // 0 .. 3,199,999 exact
    {
        float4 v = *(const float4*)(x + (size_t)i * 4);
        unsigned short t[4] = {f2bf(v.x), f2bf(v.y), f2bf(v.z), f2bf(v.w)};
        *(uint2*)(xb + (size_t)i * 4) = *(const uint2*)t;
    }
    if (i < 512) {  // zero pad rows 100000..100031
        uint4 z = {0, 0, 0, 0};
        *(uint4*)(xb + (size_t)N_NODES * DIM + i * 8) = z;
    }
    if (i < 147456) {  // Wt[(((r*4+ks)*8+t)*64+lane)*8+j] = W_r[din=ks*32+quad*8+j][dout=t*16+m16]
        int j = i & 7;
        int lane = (i >> 3) & 63;
        int t = (i >> 9) & 7;
        int ks = (i >> 12) & 3;
        int r = i >> 14;
        int m16 = lane & 15, quad = lane >> 4;
        int din = ks * 32 + quad * 8 + j;
        int dout = t * 16 + m16;
        float v = (r < 8) ? relw[(r << 14) + (din << 7) + dout] : selfw[(din << 7) + dout];
        Wt[i] = f2bf(v);
    }
    if (i < N_EDGES) atomicAdd(&degi[rel[i] * N_NODES + dst[i]], 1);
}

// Single-pass exclusive scan of degi[RN] -> offs/cursor, wave-parallel lookback.
// 98 blocks are all co-resident (<< 256 CUs) so spinning on blockIdx order is safe.
// status word: bit31=prefix-ready, bit30=aggregate-ready, low 30 bits = value.
__global__ __launch_bounds__(256) void scan_kernel(const int* __restrict__ degi,
                                                   unsigned int* __restrict__ status,
                                                   int* __restrict__ offs,
                                                   int* __restrict__ cursor) {
    __shared__ int lsum[256];
    __shared__ int lpfx;
    const int tid = threadIdx.x;
    const int b = blockIdx.x;
    const int base = b * SCAN_CHUNK + tid * 32;
    int v[32];
    int s = 0;
#pragma unroll
    for (int j = 0; j < 8; j++) {
        int idx = base + j * 4;
        int4 d = {0, 0, 0, 0};
        if (idx + 3 < RN) d = *(const int4*)(degi + idx);
        else {
            if (idx < RN) d.x = degi[idx];
            if (idx + 1 < RN) d.y = degi[idx + 1];
            if (idx + 2 < RN) d.z = degi[idx + 2];
        }
        v[j * 4] = d.x; v[j * 4 + 1] = d.y; v[j * 4 + 2] = d.z; v[j * 4 + 3] = d.w;
        s += d.x + d.y + d.z + d.w;
    }
    lsum[tid] = s;
    __syncthreads();
    for (int off = 1; off < 256; off <<= 1) {
        int p = (tid >= off) ? lsum[tid - off] : 0;
        __syncthreads();
        lsum[tid] += p;
        __syncthreads();
    }
    int thrbase = lsum[tid] - s;
    int total = lsum[255];

    if (b == 0) {
        if (tid == 0) {
            atomicExch(&status[0], 0x80000000u | (unsigned)total);
            lpfx = 0;
        }
    } else {
        if (tid == 0) atomicExch(&status[b], 0x40000000u | (unsigned)total);
        if (tid < 64) {
            int sum = 0;
            int j = b - 1;
            while (true) {
                int idx = j - tid;
                unsigned st = (idx >= 0) ? atomicAdd(&status[idx], 0u) : 0x80000000u;
                unsigned long long pball = __ballot(st & 0x80000000u);
                unsigned long long zball = __ballot(st == 0u);
                int fp = pball ? (__ffsll(pball) - 1) : 64;
                unsigned long long below = (fp >= 64) ? ~0ull : ((1ull << fp) - 1ull);
                if (zball & below) continue;         // gap not ready yet, re-read
                int lim = (fp < 64) ? fp : 63;
                int val = (tid <= lim) ? (int)(st & 0x3fffffffu) : 0;
                for (int o = 32; o > 0; o >>= 1) val += __shfl_down(val, o);
                sum += __shfl(val, 0);
                if (fp < 64) break;
                j -= 64;
            }
            if (tid == 0) {
                atomicExch(&status[b], 0x80000000u | (unsigned)(sum + total));
                lpfx = sum;
            }
        }
    }
    __syncthreads();
    int run = lpfx + thrbase;
#pragma unroll
    for (int j = 0; j < 32; j++) {
        int idx = base + j;
        if (idx < RN) {
            offs[idx] = run;
            cursor[idx] = run;
            if (idx == RN - 1) offs[RN] = run + v[j];
            run += v[j];
        }
    }
}

// Bin edges by key r*N+d; slot word = src | (d&15)<<17 (deg = segment length).
__global__ __launch_bounds__(256) void fill_kernel(const int* __restrict__ src,
                                                   const int* __restrict__ dst,
                                                   const int* __restrict__ rel,
                                                   int* __restrict__ cursor,
                                                   unsigned int* __restrict__ ebuf) {
    int e = blockIdx.x * 256 + threadIdx.x;
    if (e < N_EDGES) {
        int d = dst[e];
        int key = rel[e] * N_NODES + d;
        int pos = atomicAdd(&cursor[key], 1);
        ebuf[pos] = (unsigned int)src[e] | ((unsigned int)(d & 15) << 17);
    }
}

typedef __attribute__((ext_vector_type(8))) short frag8;
typedef __attribute__((ext_vector_type(4))) float f32x4;

// Fused aggregate+transform. Block = 64 dst rows, wave owns 16 rows; zero barriers.
// Gather: wave's 16 segments per relation are one contiguous ebuf range; edge words
// prefetched 64-wide, broadcast via readlane, row loads batched 8-deep for MLP.
__global__ __launch_bounds__(256, 4) void fused_kernel(const unsigned short* __restrict__ xb,
                                                       const unsigned short* __restrict__ Wt,
                                                       const int* __restrict__ offs2,
                                                       const unsigned int* __restrict__ ebuf,
                                                       const float* __restrict__ bias,
                                                       float* __restrict__ out) {
    __shared__ __align__(16) unsigned char ldsraw[4 * 8448];   // 33 KB

    const int tid = threadIdx.x;
    const int wave = tid >> 6, lane = tid & 63;
    const int m16 = lane & 15, quad = lane >> 4;
    const int dbase = blockIdx.x * 64 + wave * 16;
    unsigned char* slab = ldsraw + wave * 8448;

    f32x4 acc[8];
    // ---- selfloop: A-frags direct from xb (pad rows zeroed) ----
    {
#pragma unroll
        for (int t = 0; t < 8; t++) acc[t] = (f32x4){0.f, 0.f, 0.f, 0.f};
        const unsigned short* ap = xb + (size_t)(dbase + m16) * DIM;
#pragma unroll
        for (int ks = 0; ks < 4; ks++) {
            frag8 a = *(const frag8*)(ap + ks * 32 + quad * 8);
            const frag8* bp = (const frag8*)Wt + ((8 * 4 + ks) * 8) * 64 + lane;
#pragma unroll
            for (int t = 0; t < 8; t++)
                acc[t] = __builtin_amdgcn_mfma_f32_16x16x32_bf16(a, bp[t * 64], acc[t], 0, 0, 0);
        }
    }

#pragma unroll 1
    for (int r = 0; r < 8; r++) {
        int cidx = dbase + lane;
        if (cidx > N_NODES) cidx = N_NODES;
        int ob = offs2[r * N_NODES + cidx];
        int s0 = __builtin_amdgcn_readlane(ob, 0);
        int e16 = __builtin_amdgcn_readlane(ob, 16);
        int count = e16 - s0;

        // pre-zero the 4KB tile (empty segments stay zero)
        {
            uint4 z = {0, 0, 0, 0};
            *(uint4*)(slab + lane * 16) = z;
            *(uint4*)(slab + 1024 + lane * 16) = z;
            *(uint4*)(slab + 2048 + lane * 16) = z;
            *(uint4*)(slab + 3072 + lane * 16) = z;
        }

        if (count > 0) {
            float ax = 0.f, ay = 0.f;
            int cur = -1, cnt = 0;
#pragma unroll 1
            for (int b0 = 0; b0 < count; b0 += 64) {
                int cl = count - b0; if (cl > 64) cl = 64;
                unsigned int ew = 0;
                if (b0 + lane < count) ew = ebuf[s0 + b0 + lane];
#pragma unroll 1
                for (int i = 0; i < cl; i += 8) {
                    int kk = cl - i; if (kk > 8) kk = 8;
                    unsigned int u[8], v[8];
#pragma unroll
                    for (int k = 0; k < 8; k++) {        // branchless clamped loads: 8-deep MLP
                        int li = i + k; if (li >= cl) li = cl - 1;
                        u[k] = (unsigned int)__builtin_amdgcn_readlane((int)ew, li);
                        v[k] = *((const unsigned int*)xb + (size_t)(u[k] & 0x1ffffu) * 64 + lane);
                    }
#pragma unroll
                    for (int k = 0; k < 8; k++) {
                        if (k < kk) {                    // wave-uniform guard
                            int dl = (int)((u[k] >> 17) & 15u);
                            if (dl != cur) {
                                if (cnt > 0) {
                                    float inv = 1.0f / (float)cnt;
                                    unsigned int p = (unsigned int)f2bf(ax * inv) |
                                                     ((unsigned int)f2bf(ay * inv) << 16);
                                    int bb = (lane >> 2) ^ cur;
                                    *(unsigned int*)(slab + cur * 256 + bb * 16 + (lane & 3) * 4) = p;
                                }
                                cur = dl; ax = 0.f; ay = 0.f; cnt = 0;
                            }
                            ax += bf2f((unsigned short)(v[k] & 0xffffu));
                            ay += bf2f((unsigned short)(v[k] >> 16));
                            cnt++;
                        }
                    }
                }
            }
            {   // final flush (cnt>0 since count>0)
                float inv = 1.0f / (float)cnt;
                unsigned int p = (unsigned int)f2bf(ax * inv) |
                                 ((unsigned int)f2bf(ay * inv) << 16);
                int bb = (lane >> 2) ^ cur;
                *(unsigned int*)(slab + cur * 256 + bb * 16 + (lane & 3) * 4) = p;
            }
        }

        // A-frags from swizzled tile + MFMA (LDS ops in-order per wave; no barrier)
#pragma unroll
        for (int ks = 0; ks < 4; ks++) {
            int bb = (4 * ks + quad) ^ m16;
            frag8 a = *(const frag8*)(slab + m16 * 256 + bb * 16);
            const frag8* bp = (const frag8*)Wt + ((r * 4 + ks) * 8) * 64 + lane;
#pragma unroll
            for (int t = 0; t < 8; t++)
                acc[t] = __builtin_amdgcn_mfma_f32_16x16x32_bf16(a, bp[t * 64], acc[t], 0, 0, 0);
        }
    }

    // ---- epilogue: +bias, wave-private fp32 repack (stride 132), coalesced store
    float* S = (float*)slab;
#pragma unroll
    for (int t = 0; t < 8; t++) {
        float bc = bias[t * 16 + m16];
#pragma unroll
        for (int i = 0; i < 4; i++)
            S[(quad * 4 + i) * 132 + t * 16 + m16] = acc[t][i] + bc;
    }
#pragma unroll
    for (int c = 0; c < 8; c++) {
        int row16 = c * 2 + (lane >> 5);
        int g = dbase + row16;
        if (g < N_NODES)
            *(float4*)(out + (size_t)g * DIM + (lane & 31) * 4) =
                *(float4*)(S + row16 * 132 + (lane & 31) * 4);
    }
}

extern "C" void kernel_launch(void* const* d_in, const int* in_sizes, int n_in,
                              void* d_out, int out_size, void* d_ws, size_t ws_size,
                              hipStream_t stream) {
    const float* x = (const float*)d_in[0];
    const int* edge_index = (const int*)d_in[1]; // [2][E]: src then dst
    const int* edge_type = (const int*)d_in[2];
    const float* relw = (const float*)d_in[3];
    const float* selfw = (const float*)d_in[4];
    const float* bias = (const float*)d_in[5];
    float* out = (float*)d_out;
    (void)in_sizes; (void)n_in; (void)out_size; (void)ws_size;

    // ws: xb 25.6MB | Wt 0.29MB | offs2 3.2MB | ebuf 2.5MB
    char* ws = (char*)d_ws;
    size_t off = 0;
    unsigned short* xb = (unsigned short*)(ws + off); off += (size_t)N_PADROWS * DIM * 2;
    unsigned short* Wt = (unsigned short*)(ws + off); off += (size_t)9 * DIM * DIM * 2;
    int* offs2 = (int*)(ws + off); off += (size_t)(RN + 4) * 4;
    unsigned int* ebuf = (unsigned int*)(ws + off); off += (size_t)N_EDGES * 4;

    // pre-fused scratch in d_out (fused_kernel overwrites all of out at the end):
    // degi[RN] | status[SCAN_BLOCKS+1] | cursor[RN]
    int* degi = (int*)d_out;
    unsigned int* status = (unsigned int*)(degi + RN);
    int* cursor = (int*)(status + SCAN_BLOCKS + 2);

    const int* src = edge_index;
    const int* dst = edge_index + N_EDGES;

    hipMemsetAsync(degi, 0, (size_t)RN * 4 + (SCAN_BLOCKS + 2) * 4, stream);
    prep_kernel<<<12500, 256, 0, stream>>>(x, relw, selfw, dst, edge_type, xb, Wt, degi);
    scan_kernel<<<SCAN_BLOCKS, 256, 0, stream>>>(degi, status, offs2, cursor);
    fill_kernel<<<(N_EDGES + 255) / 256, 256, 0, stream>>>(src, dst, edge_type, cursor, ebuf);
    fused_kernel<<<N_PADROWS / 64, 256, 0, stream>>>(xb, Wt, offs2, ebuf, bias, out);
}